// Round 10
// baseline (68.929 us; speedup 1.0000x reference)
//
#include <hip/hip_runtime.h>

// Periodogram: out[b,m] = (re^2 + im^2)/N,  re = aC + bS, im = bC - aS
// f16 MFMA GEMMs. r10: trig B-operand generated ENTIRELY in registers via
// per-lane packed-f16 rotation constants (depth-2 chains, no LDS round-trip
// for C/S). LDS holds only A/B (16 KB, single buffer, 2 barriers/step).

typedef __fp16 half8  __attribute__((ext_vector_type(8)));
typedef __fp16 half2v __attribute__((ext_vector_type(2)));
typedef float  f32x4  __attribute__((ext_vector_type(4)));

#define B_SZ 512
#define N_SZ 1024
#define M_SZ 16384
#define BT 128
#define MT 128
#define KT 32

union U2 { half2v h2[2]; uint2 u; };
union BF { half2v h2[4]; half8 v; uint4 u; };

__global__ __launch_bounds__(256, 2)
void periodogram_kernel(const float* __restrict__ x, const float* __restrict__ xgrid,
                        float* __restrict__ out) {
    __shared__ __align__(16) unsigned char smem[2 * 8192];   // A | B only
    const int tid  = (int)threadIdx.x;
    const int lane = tid & 63;
    const int w    = tid >> 6;
    const int bid  = (int)blockIdx.x;
    const int b0 = (bid & 3) * BT;
    const int m0 = (bid >> 2) * MT;

    const int wr = (w >> 1) * 64;   // wave row offset in tile
    const int wc = (w & 1) * 64;    // wave col offset in tile

    // ---- staging assignment: thread -> rows {row8+32*rep}, k-chunk kk ----
    const int row8 = tid >> 3;          // 0..31
    const int kk   = (tid & 7) * 4;     // 0,4,...,28
    const int g    = kk >> 3;           // 0..3
    const int kkh  = (kk >> 2) & 1;     // 8B half of the 16B cell

    unsigned woff[4];
    const float* srcA[4];
#pragma unroll
    for (int rep = 0; rep < 4; ++rep) {
        const int row = row8 + rep * 32;
        const int rb = row >> 4, r16 = row & 15;
        woff[rep] = (unsigned)(rb * 1024 + ((g * 16 + (r16 ^ (g << 1))) << 4) + kkh * 8);
        srcA[rep] = x + (size_t)(b0 + row) * 2048 + kk;
    }

    // ---- per-lane trig state for the B operand (register-resident) ----
    // lane holds col = wc + fn*16 + (lane&15), k = g8 + j (g8 = (lane>>4)*8),
    // advanced by 32 per K-step. Packed-f16 rotation constants for j=0..7.
    half2v PC[4][4], PS[4][4];
    float c0v[4], s0v[4], C32[4], S32[4];
    const float g8f = (float)((lane >> 4) << 3);
#pragma unroll
    for (int fn = 0; fn < 4; ++fn) {
        const float xg = xgrid[m0 + wc + fn * 16 + (lane & 15)];
        float Cj[8], Sj[8];
        Cj[0] = 1.0f; Sj[0] = 0.0f;
#pragma unroll
        for (int j = 1; j < 8; ++j) {
            float p = xg * (float)j; p -= floorf(p);
            Cj[j] = __builtin_amdgcn_cosf(p);   // cos(2*pi*p)
            Sj[j] = __builtin_amdgcn_sinf(p);
        }
#pragma unroll
        for (int i = 0; i < 4; ++i) {
            PC[fn][i] = __builtin_amdgcn_cvt_pkrtz(Cj[2 * i], Cj[2 * i + 1]);
            PS[fn][i] = __builtin_amdgcn_cvt_pkrtz(Sj[2 * i], Sj[2 * i + 1]);
        }
        float p32 = xg * 32.0f; p32 -= floorf(p32);      // exact product
        C32[fn] = __builtin_amdgcn_cosf(p32);
        S32[fn] = __builtin_amdgcn_sinf(p32);
        float pb = xg * g8f; pb -= floorf(pb);
        c0v[fn] = __builtin_amdgcn_cosf(pb);
        s0v[fn] = __builtin_amdgcn_sinf(pb);
    }

    f32x4 accRe[4][4], accIm[4][4];
#pragma unroll
    for (int i = 0; i < 4; ++i)
#pragma unroll
        for (int j = 0; j < 4; ++j) { accRe[i][j] = (f32x4)0.0f; accIm[i][j] = (f32x4)0.0f; }

    // ---- fragment read bases (swizzled lane->cell) ----
    const unsigned roff  = (unsigned)((lane ^ ((lane >> 4) << 1)) << 4);
    const unsigned aBase = 0u    + ((unsigned)(wr >> 4) << 10) + roff;
    const unsigned bBase = 8192u + ((unsigned)(wr >> 4) << 10) + roff;

    for (int t = 0; t < N_SZ / KT; ++t) {
        const int k0 = t * KT;
        // ---- issue A/B global loads (f32) before the barrier ----
        float4 va[4], vb[4];
#pragma unroll
        for (int rep = 0; rep < 4; ++rep) {
            va[rep] = *(const float4*)(srcA[rep] + k0);
            vb[rep] = *(const float4*)(srcA[rep] + k0 + 1024);
        }
        __syncthreads();   // previous iteration's fragment reads done
        // ---- stage A/B to LDS as f16 ----
#pragma unroll
        for (int rep = 0; rep < 4; ++rep) {
            U2 pa, pb;
            pa.h2[0] = __builtin_amdgcn_cvt_pkrtz(va[rep].x, va[rep].y);
            pa.h2[1] = __builtin_amdgcn_cvt_pkrtz(va[rep].z, va[rep].w);
            pb.h2[0] = __builtin_amdgcn_cvt_pkrtz(vb[rep].x, vb[rep].y);
            pb.h2[1] = __builtin_amdgcn_cvt_pkrtz(vb[rep].z, vb[rep].w);
            *(uint2*)(smem + 0    + woff[rep]) = pa.u;
            *(uint2*)(smem + 8192 + woff[rep]) = pb.u;
        }
        __syncthreads();
        // ---- compute: A from LDS, trig generated in-register ----
        half8 fa[4], fb[4];
#pragma unroll
        for (int fm = 0; fm < 4; ++fm) {
            fa[fm] = *(const half8*)(smem + aBase + fm * 1024);
            fb[fm] = *(const half8*)(smem + bBase + fm * 1024);
        }
#pragma unroll
        for (int fn = 0; fn < 4; ++fn) {
            const float c0 = c0v[fn], s0 = s0v[fn];
            const half2v c0b = __builtin_amdgcn_cvt_pkrtz(c0, c0);
            const half2v s0b = __builtin_amdgcn_cvt_pkrtz(s0, s0);
            BF fc, fs, fns;
#pragma unroll
            for (int i = 0; i < 4; ++i) {
                fc.h2[i] = c0b * PC[fn][i] - s0b * PS[fn][i];   // pk_mul+pk_fma
                fs.h2[i] = s0b * PC[fn][i] + c0b * PS[fn][i];
            }
            fns.u.x = fs.u.x ^ 0x80008000u;
            fns.u.y = fs.u.y ^ 0x80008000u;
            fns.u.z = fs.u.z ^ 0x80008000u;
            fns.u.w = fs.u.w ^ 0x80008000u;
#pragma unroll
            for (int fm = 0; fm < 4; ++fm) {
                accRe[fm][fn] = __builtin_amdgcn_mfma_f32_16x16x32_f16(fa[fm], fc.v,  accRe[fm][fn], 0, 0, 0);
                accRe[fm][fn] = __builtin_amdgcn_mfma_f32_16x16x32_f16(fb[fm], fs.v,  accRe[fm][fn], 0, 0, 0);
                accIm[fm][fn] = __builtin_amdgcn_mfma_f32_16x16x32_f16(fb[fm], fc.v,  accIm[fm][fn], 0, 0, 0);
                accIm[fm][fn] = __builtin_amdgcn_mfma_f32_16x16x32_f16(fa[fm], fns.v, accIm[fm][fn], 0, 0, 0);
            }
            // advance base state by Delta-k = 32 (f32, depth-2)
            c0v[fn] = __builtin_fmaf(c0, C32[fn], -(s0 * S32[fn]));
            s0v[fn] = __builtin_fmaf(s0, C32[fn],  (c0 * S32[fn]));
        }
    }

    // ---- epilogue: out = (re^2 + im^2)/N ----
    // D frag layout (measured m89): col = lane&15, row = (lane>>4)*4 + reg
    const float inv = 1.0f / (float)N_SZ;
    const int orow0 = b0 + wr + ((lane >> 4) << 2);
    const int ocol0 = m0 + wc + (lane & 15);
#pragma unroll
    for (int fm = 0; fm < 4; ++fm)
#pragma unroll
        for (int fn = 0; fn < 4; ++fn) {
            const f32x4 r = accRe[fm][fn];
            const f32x4 im = accIm[fm][fn];
            const int col = ocol0 + fn * 16;
#pragma unroll
            for (int j = 0; j < 4; ++j) {
                const int row = orow0 + fm * 16 + j;
                out[(size_t)row * M_SZ + col] = (r[j] * r[j] + im[j] * im[j]) * inv;
            }
        }
}

extern "C" void kernel_launch(void* const* d_in, const int* in_sizes, int n_in,
                              void* d_out, int out_size, void* d_ws, size_t ws_size,
                              hipStream_t stream) {
    const float* x     = (const float*)d_in[0];
    const float* xgrid = (const float*)d_in[1];
    float* out = (float*)d_out;
    dim3 grid(B_SZ / BT * (M_SZ / MT));   // 4 * 128 = 512 blocks
    dim3 block(256);
    periodogram_kernel<<<grid, block, 0, stream>>>(x, xgrid, out);
}